// Round 11
// baseline (200.449 us; speedup 1.0000x reference)
//
#include <hip/hip_runtime.h>

// B*H*W = 65536 vectors, dim 64, 512 codes
#define NVEC 65536
#define DIM 64
#define KCODES 512
#define VPB 64        // vectors per block
#define NBLK 1024     // NVEC / VPB
#define ELS 2048.0f   // residual pre-scale (avoids fp16 denormals)
#define INV_ELS (1.0f / 2048.0f)
#define GAP_THR 2e-4f // rescore guard: >> max split-fp16 ordering error (~1.5e-5)

typedef _Float16 f16x8 __attribute__((ext_vector_type(8)));
typedef float    f32x4 __attribute__((ext_vector_type(4)));

// ws layout (floats):
#define WS_EN   4                   // [4..516) codebook norms
#define WS_EH   1024                // [1024..17408) hi fp16 B-fragments
#define WS_EL   (1024 + 16384)      // [17408..33792) residual fp16 B-fragments
#define WS_PART 33792               // [33792..34816) per-block loss partials (1024)
#define WS_EMBT 34816               // [34816..67584) embT[k][d]

// Prep (17 blocks x 512): b=0 norms; b=1..8 MFMA B-fragments (hi + scaled
// residual); b=9..16 transpose emb -> embT[k][d] via LDS tile.
__global__ __launch_bounds__(512, 1) void prep_kernel(const float* __restrict__ emb,
                                                      float* __restrict__ ws) {
    const int tid = threadIdx.x;
    const int b   = blockIdx.x;
    if (b == 0) {
        float s = 0.f;
#pragma unroll
        for (int d = 0; d < DIM; ++d) { float v = emb[d * KCODES + tid]; s = fmaf(v, v, s); }
        ws[WS_EN + tid] = s;
    } else if (b <= 8) {
        const int fl = (b - 1) * 512 + tid;            // fragment-lane id, 0..4095
        const int ct = fl >> 7, s5 = (fl >> 6) & 1, l = fl & 63;
        const int k  = ct * 16 + (l & 15);             // B col
        const int d0 = s5 * 32 + (l >> 4) * 8;         // B k-rows (d)
        f16x8 eh, el;
#pragma unroll
        for (int e = 0; e < 8; ++e) {
            float v = emb[(d0 + e) * KCODES + k];
            _Float16 h = (_Float16)v;
            eh[e] = h;
            el[e] = (_Float16)((v - (float)h) * ELS);
        }
        ((f16x8*)(ws + WS_EH))[fl] = eh;
        ((f16x8*)(ws + WS_EL))[fl] = el;
    } else {
        __shared__ float tl[64][65];
        const int kt = b - 9;          // k-tile 0..7
        const int r  = tid >> 3;       // 0..63
        const int g  = tid & 7;
#pragma unroll
        for (int i = 0; i < 8; ++i)
            tl[r][g * 8 + i] = emb[r * KCODES + kt * 64 + g * 8 + i];
        __syncthreads();
#pragma unroll
        for (int i = 0; i < 8; ++i)
            ws[WS_EMBT + (kt * 64 + r) * 64 + g * 8 + i] = tl[g * 8 + i][r];
    }
}

// Main: 512 thr = 8 waves, 64 vectors/block, grid 1024 = 4 blocks/CU =
// 8 waves/SIMD (TLP doubled vs R9/R10). Wave pair (wid>>1) owns 16 vectors;
// wid&1 selects a 256-code half-stream (NTILE=16), register double-buffered,
// NO main-loop barriers. Half-0 owns lower k -> lexicographic (dist,k) merge
// preserves reference first-min tie-break. Split-fp16 6-MFMA per tile;
// zn-free approx score; exact fp32 rescore when approx gap <= GAP_THR.
__global__ __launch_bounds__(512, 8) void vq_kernel(const float* __restrict__ x,
                                                    const float* __restrict__ ws_ro,
                                                    float* __restrict__ out,
                                                    float* __restrict__ part) {
    __shared__ f16x8 zhS[VPB][8];   // [v][u], u = (d>>3) ^ (v&7)  (bank swizzle)
    __shared__ f16x8 zlS[VPB][8];
    __shared__ float enS[KCODES];
    __shared__ float sdf1[2][VPB], sdf2[2][VPB];
    __shared__ int   k1a[2][VPB],  k2a[2][VPB];
    __shared__ int   cand[VPB][2];
    __shared__ float sdfm[VPB][2];
    __shared__ float exd[VPB][2];
    __shared__ int   bksel[VPB];
    __shared__ float swl[8];

    const int tid  = threadIdx.x;
    const int wid  = tid >> 6;            // 0..7
    const int lane = tid & 63;
    const size_t xbase = (size_t)blockIdx.x * VPB * DIM;

    enS[tid] = ws_ro[WS_EN + tid];        // 512 threads, one code each

    // x-block -> fp16 hi + scaled residual into swizzled LDS (8 thr/vector)
    {
        const int v  = tid >> 3;          // 0..63
        const int d0 = (tid & 7) * 8;
        const float* xp = x + xbase + v * DIM + d0;
        float4 a = *(const float4*)(xp);
        float4 b = *(const float4*)(xp + 4);
        float t0[8] = {a.x, a.y, a.z, a.w, b.x, b.y, b.z, b.w};
        f16x8 h0, l0;
#pragma unroll
        for (int i = 0; i < 8; ++i) {
            _Float16 h = (_Float16)t0[i];
            h0[i] = h;
            l0[i] = (_Float16)((t0[i] - (float)h) * ELS);
        }
        const int u0 = (d0 >> 3) ^ (v & 7);
        zhS[v][u0] = h0;
        zlS[v][u0] = l0;
    }
    __syncthreads();

    // A-fragments: row = lane&15 (vector), k = (lane>>4)*8 + e (+32 for 2nd)
    const int half = wid & 1;             // code half: 0 -> k<256, 1 -> k>=256
    const int vb   = (wid >> 1) * 16;
    const int vA   = vb + (lane & 15);
    const int g4   = lane >> 4;
    const int sw   = vA & 7;
    f16x8 ah0 = zhS[vA][(g4)     ^ sw];
    f16x8 ah1 = zhS[vA][(4 + g4) ^ sw];
    f16x8 al0 = zlS[vA][(g4)     ^ sw];
    f16x8 al1 = zlS[vA][(4 + g4) ^ sw];

    const f16x8* ehp = (const f16x8*)(ws_ro + WS_EH);
    const f16x8* elp = (const f16x8*)(ws_ro + WS_EL);
    const int fb  = half * 2048;          // 16 tiles * 2 * 64 fragments per half
    const int kb0 = half * 256;

    float best[4]  = {3.4e38f, 3.4e38f, 3.4e38f, 3.4e38f};
    float best2[4] = {3.4e38f, 3.4e38f, 3.4e38f, 3.4e38f};
    int   bk1[4]   = {0, 0, 0, 0};
    int   bk2[4]   = {0, 0, 0, 0};

    // register double-buffer of B-fragments (1-tile lookahead, no barriers)
    f16x8 cbh0 = ehp[fb + lane],       cbh1 = ehp[fb + 64 + lane];
    f16x8 cbl0 = elp[fb + lane],       cbl1 = elp[fb + 64 + lane];

#pragma unroll 1
    for (int ct = 0; ct < 16; ++ct) {
        f16x8 nbh0, nbh1, nbl0, nbl1;
        if (ct < 15) {                    // issue next tile's loads early
            const int o = fb + (ct * 2 + 2) * 64 + lane;
            nbh0 = ehp[o]; nbh1 = ehp[o + 64];
            nbl0 = elp[o]; nbl1 = elp[o + 64];
        }
        f32x4 acch = {0.f, 0.f, 0.f, 0.f};
        f32x4 accm = {0.f, 0.f, 0.f, 0.f};
        acch = __builtin_amdgcn_mfma_f32_16x16x32_f16(ah0, cbh0, acch, 0, 0, 0);
        acch = __builtin_amdgcn_mfma_f32_16x16x32_f16(ah1, cbh1, acch, 0, 0, 0);
        accm = __builtin_amdgcn_mfma_f32_16x16x32_f16(al0, cbh0, accm, 0, 0, 0);
        accm = __builtin_amdgcn_mfma_f32_16x16x32_f16(al1, cbh1, accm, 0, 0, 0);
        accm = __builtin_amdgcn_mfma_f32_16x16x32_f16(ah0, cbl0, accm, 0, 0, 0);
        accm = __builtin_amdgcn_mfma_f32_16x16x32_f16(ah1, cbl1, accm, 0, 0, 0);
        const int   kk  = kb0 + ct * 16 + (lane & 15);   // C/D col = lane&15
        const float enk = enS[kk];
#pragma unroll
        for (int j = 0; j < 4; ++j) {
            // zn-free approx score: en[k] - 2*dot (ordering-equivalent)
            float dot = fmaf(accm[j], INV_ELS, acch[j]);
            float sc  = fmaf(-2.0f, dot, enk);
            bool  c1  = sc < best[j];
            bool  c2  = sc < best2[j];
            bk2[j]    = c1 ? bk1[j] : (c2 ? kk : bk2[j]);
            best2[j]  = fminf(best2[j], fmaxf(sc, best[j]));
            bk1[j]    = c1 ? kk : bk1[j];
            best[j]   = fminf(sc, best[j]);
        }
        if (ct < 15) { cbh0 = nbh0; cbh1 = nbh1; cbl0 = nbl0; cbl1 = nbl1; }
    }

    // top-2 (with indices) merge across the 16 lanes sharing each vector row
#pragma unroll
    for (int m = 1; m <= 8; m <<= 1) {
#pragma unroll
        for (int j = 0; j < 4; ++j) {
            float qb  = __shfl_xor(best[j],  m);
            int   qk  = __shfl_xor(bk1[j],   m);
            float q2  = __shfl_xor(best2[j], m);
            int   qk2 = __shfl_xor(bk2[j],   m);
            bool  t1  = (qb < best[j]) || (qb == best[j] && qk < bk1[j]);
            float lb  = t1 ? best[j] : qb;      // losing first
            int   lk  = t1 ? bk1[j]  : qk;
            float nb  = t1 ? qb : best[j];      // winning first
            int   nk  = t1 ? qk : bk1[j];
            bool  ta  = (best2[j] < q2) || (best2[j] == q2 && bk2[j] < qk2);
            float sb  = ta ? best2[j] : q2;
            int   sk  = ta ? bk2[j]   : qk2;
            bool  tb  = (lb < sb) || (lb == sb && lk < sk);
            best2[j]  = tb ? lb : sb;
            bk2[j]    = tb ? lk : sk;
            best[j]   = nb;
            bk1[j]    = nk;
        }
    }
    {
        const int j = lane & 15;
        if (j < 4) {
            const int v = vb + g4 * 4 + j;
            sdf1[half][v] = best[j];
            sdf2[half][v] = best2[j];
            k1a[half][v]  = bk1[j];
            k2a[half][v]  = bk2[j];
        }
    }
    __syncthreads();

    // merge the two code-halves per vector (lex (dist,k): half-0 ks lower)
    if (tid < VPB) {
        const float a1 = sdf1[0][tid]; const int ka1 = k1a[0][tid];
        const float a2 = sdf2[0][tid]; const int ka2 = k2a[0][tid];
        const float c1 = sdf1[1][tid]; const int kc1 = k1a[1][tid];
        const float c2 = sdf2[1][tid]; const int kc2 = k2a[1][tid];
        const bool afirst = (a1 < c1) || (a1 == c1 && ka1 < kc1);
        const float f1 = afirst ? a1 : c1;  const int fk1 = afirst ? ka1 : kc1;
        const float u  = afirst ? a2 : c2;  const int uk  = afirst ? ka2 : kc2; // winner's 2nd
        const float w  = afirst ? c1 : a1;  const int wk  = afirst ? kc1 : ka1; // loser's 1st
        const bool usec = (u < w) || (u == w && uk < wk);
        cand[tid][0] = fk1;               sdfm[tid][0] = f1;
        cand[tid][1] = usec ? uk : wk;    sdfm[tid][1] = usec ? u : w;
    }
    __syncthreads();

    // conditional exact rescore (reference-exact chain; zn computed inline)
    if (tid < 2 * VPB) {
        const int v = tid >> 1, cc = tid & 1;
        float res = sdfm[v][cc];
        if (sdfm[v][1] - sdfm[v][0] <= GAP_THR) {
            const int k = cand[v][cc];
            const float* xr = x + xbase + v * DIM;
            const float* er = ws_ro + WS_EMBT + k * 64;
            float zn = 0.f, dot = 0.f;
#pragma unroll
            for (int d = 0; d < DIM; ++d) {
                float xv = xr[d];
                zn  = fmaf(xv, xv, zn);
                dot = fmaf(xv, er[d], dot);
            }
            res = fmaf(-2.0f, dot, zn + enS[k]);
        }
        exd[v][cc] = res;
    }
    __syncthreads();
    if (tid < VPB) {
        const int k0 = cand[tid][0], k1 = cand[tid][1];
        const float d0 = exd[tid][0], d1 = exd[tid][1];
        const bool take2 = (d1 < d0) || (d1 == d0 && k1 < k0);
        bksel[tid] = take2 ? k1 : k0;
    }
    __syncthreads();

    // epilogue: thread -> (vector v16, dim-block j8); q from embT rows
    const int v16 = tid >> 3;             // 0..63
    const int j8  = (tid & 7) * 8;
    const int bk  = bksel[v16];
    const int gvec = blockIdx.x * VPB + v16;
    const float*  xg  = x + (size_t)gvec * DIM + j8;
    float*        og  = out + (size_t)gvec * DIM + j8;
    const float4* et4 = (const float4*)(ws_ro + WS_EMBT + bk * 64);

    float lossLocal = 0.f;
#pragma unroll
    for (int c = 0; c < 2; ++c) {
        float4 q  = et4[(tid & 7) * 2 + c];
        *(float4*)(og + c * 4) = q;
        float4 xa = *(const float4*)(xg + c * 4);
        float a;
        a = q.x - xa.x; lossLocal = fmaf(a, a, lossLocal);
        a = q.y - xa.y; lossLocal = fmaf(a, a, lossLocal);
        a = q.z - xa.z; lossLocal = fmaf(a, a, lossLocal);
        a = q.w - xa.w; lossLocal = fmaf(a, a, lossLocal);
    }

    // block-reduce loss -> one partial store per block (no atomics)
#pragma unroll
    for (int off = 32; off; off >>= 1) lossLocal += __shfl_down(lossLocal, off, 64);
    if (lane == 0) swl[wid] = lossLocal;
    __syncthreads();
    if (tid == 0) {
        float s = 0.f;
#pragma unroll
        for (int i = 0; i < 8; ++i) s += swl[i];
        part[WS_PART + blockIdx.x] = s;
    }
}

// Finish: reduce 1024 per-block partials, write the loss element.
__global__ __launch_bounds__(256, 1) void finish_kernel(const float* __restrict__ part,
                                                        float* __restrict__ out) {
    __shared__ float sw[4];
    const int tid = threadIdx.x, lane = tid & 63, wid = tid >> 6;
    float s = part[WS_PART + tid]       + part[WS_PART + tid + 256]
            + part[WS_PART + tid + 512] + part[WS_PART + tid + 768];
#pragma unroll
    for (int off = 32; off; off >>= 1) s += __shfl_down(s, off, 64);
    if (lane == 0) sw[wid] = s;
    __syncthreads();
    if (tid == 0) {
        float total = sw[0] + sw[1] + sw[2] + sw[3];
        out[(size_t)NVEC * DIM] = 2.0f * total / (float)((size_t)NVEC * DIM);
    }
}

extern "C" void kernel_launch(void* const* d_in, const int* in_sizes, int n_in,
                              void* d_out, int out_size, void* d_ws, size_t ws_size,
                              hipStream_t stream) {
    const float* x   = (const float*)d_in[0];
    const float* emb = (const float*)d_in[1];
    float* out = (float*)d_out;
    float* ws  = (float*)d_ws;

    prep_kernel<<<dim3(17), dim3(512), 0, stream>>>(emb, ws);
    vq_kernel<<<dim3(NBLK), dim3(512), 0, stream>>>(x, ws, out, ws);
    finish_kernel<<<dim3(1), dim3(256), 0, stream>>>(ws, out);
}

// Round 12
// 60.591 us; speedup vs baseline: 3.3082x; 3.3082x over previous
//
#include <hip/hip_runtime.h>

// B*H*W = 65536 vectors, dim 64, 512 codes
#define NVEC 65536
#define DIM 64
#define KCODES 512
#define VPB 64        // vectors per block
#define NBLK 1024     // NVEC / VPB
#define ELS 2048.0f   // residual pre-scale (avoids fp16 denormals)
#define INV_ELS (1.0f / 2048.0f)
#define GAP_THR 2e-4f // rescore guard: >> max split-fp16 ordering error (~1.5e-5)

typedef _Float16 f16x8 __attribute__((ext_vector_type(8)));
typedef float    f32x4 __attribute__((ext_vector_type(4)));

// ws layout (floats):
#define WS_EN   4                   // [4..516) codebook norms
#define WS_EH   1024                // [1024..17408) hi fp16 B-fragments
#define WS_EL   (1024 + 16384)      // [17408..33792) residual fp16 B-fragments
#define WS_PART 33792               // [33792..34816) per-block loss partials (1024)
#define WS_EMBT 34816               // [34816..67584) embT[k][d]

// Prep (17 blocks x 512): b=0 norms; b=1..8 MFMA B-fragments (hi + scaled
// residual); b=9..16 transpose emb -> embT[k][d] via LDS tile.
__global__ __launch_bounds__(512, 1) void prep_kernel(const float* __restrict__ emb,
                                                      float* __restrict__ ws) {
    const int tid = threadIdx.x;
    const int b   = blockIdx.x;
    if (b == 0) {
        float s = 0.f;
#pragma unroll
        for (int d = 0; d < DIM; ++d) { float v = emb[d * KCODES + tid]; s = fmaf(v, v, s); }
        ws[WS_EN + tid] = s;
    } else if (b <= 8) {
        const int fl = (b - 1) * 512 + tid;            // fragment-lane id, 0..4095
        const int ct = fl >> 7, s5 = (fl >> 6) & 1, l = fl & 63;
        const int k  = ct * 16 + (l & 15);             // B col
        const int d0 = s5 * 32 + (l >> 4) * 8;         // B k-rows (d)
        f16x8 eh, el;
#pragma unroll
        for (int e = 0; e < 8; ++e) {
            float v = emb[(d0 + e) * KCODES + k];
            _Float16 h = (_Float16)v;
            eh[e] = h;
            el[e] = (_Float16)((v - (float)h) * ELS);
        }
        ((f16x8*)(ws + WS_EH))[fl] = eh;
        ((f16x8*)(ws + WS_EL))[fl] = el;
    } else {
        __shared__ float tl[64][65];
        const int kt = b - 9;          // k-tile 0..7
        const int r  = tid >> 3;       // 0..63
        const int g  = tid & 7;
#pragma unroll
        for (int i = 0; i < 8; ++i)
            tl[r][g * 8 + i] = emb[r * KCODES + kt * 64 + g * 8 + i];
        __syncthreads();
#pragma unroll
        for (int i = 0; i < 8; ++i)
            ws[WS_EMBT + (kt * 64 + r) * 64 + g * 8 + i] = tl[g * 8 + i][r];
    }
}

// Main: 512 thr = 8 waves, 64 vectors/block, grid 1024. Wave pair (wid>>1)
// owns 16 vectors; wid&1 selects a 256-code half-stream (16 tiles), register
// double-buffered, NO main-loop barriers. launch_bounds(512,4): 128-VGPR
// budget -> natural ~52-VGPR allocation (R9-measured), and since 52<=64 the
// HW still schedules 8 waves/SIMD (R11's (512,8) forced a 32-VGPR split ->
// 450MB scratch spill). Half-0 owns lower k -> lex (dist,k) merge preserves
// reference first-min tie-break. Split-fp16 6-MFMA tiles; zn-free approx
// score; exact fp32 rescore when approx gap <= GAP_THR. No atomics.
__global__ __launch_bounds__(512, 4) void vq_kernel(const float* __restrict__ x,
                                                    const float* __restrict__ ws_ro,
                                                    float* __restrict__ out,
                                                    float* __restrict__ part) {
    __shared__ f16x8 zhS[VPB][8];   // [v][u], u = (d>>3) ^ (v&7)  (bank swizzle)
    __shared__ f16x8 zlS[VPB][8];
    __shared__ float enS[KCODES];
    __shared__ float sdf1[2][VPB], sdf2[2][VPB];
    __shared__ int   k1a[2][VPB],  k2a[2][VPB];
    __shared__ int   cand[VPB][2];
    __shared__ float sdfm[VPB][2];
    __shared__ float exd[VPB][2];
    __shared__ int   bksel[VPB];
    __shared__ float swl[8];

    const int tid  = threadIdx.x;
    const int wid  = tid >> 6;            // 0..7
    const int lane = tid & 63;
    const size_t xbase = (size_t)blockIdx.x * VPB * DIM;

    enS[tid] = ws_ro[WS_EN + tid];        // 512 threads, one code each

    // x-block -> fp16 hi + scaled residual into swizzled LDS (8 thr/vector)
    {
        const int v  = tid >> 3;          // 0..63
        const int d0 = (tid & 7) * 8;
        const float* xp = x + xbase + v * DIM + d0;
        float4 a = *(const float4*)(xp);
        float4 b = *(const float4*)(xp + 4);
        float t0[8] = {a.x, a.y, a.z, a.w, b.x, b.y, b.z, b.w};
        f16x8 h0, l0;
#pragma unroll
        for (int i = 0; i < 8; ++i) {
            _Float16 h = (_Float16)t0[i];
            h0[i] = h;
            l0[i] = (_Float16)((t0[i] - (float)h) * ELS);
        }
        const int u0 = (d0 >> 3) ^ (v & 7);
        zhS[v][u0] = h0;
        zlS[v][u0] = l0;
    }
    __syncthreads();

    // A-fragments: row = lane&15 (vector), k = (lane>>4)*8 + e (+32 for 2nd)
    const int half = wid & 1;             // code half: 0 -> k<256, 1 -> k>=256
    const int vb   = (wid >> 1) * 16;
    const int vA   = vb + (lane & 15);
    const int g4   = lane >> 4;
    const int sw   = vA & 7;
    f16x8 ah0 = zhS[vA][(g4)     ^ sw];
    f16x8 ah1 = zhS[vA][(4 + g4) ^ sw];
    f16x8 al0 = zlS[vA][(g4)     ^ sw];
    f16x8 al1 = zlS[vA][(4 + g4) ^ sw];

    const f16x8* ehp = (const f16x8*)(ws_ro + WS_EH);
    const f16x8* elp = (const f16x8*)(ws_ro + WS_EL);
    const int fb  = half * 2048;          // 16 tiles * 2 * 64 fragments per half
    const int kb0 = half * 256;

    float best[4]  = {3.4e38f, 3.4e38f, 3.4e38f, 3.4e38f};
    float best2[4] = {3.4e38f, 3.4e38f, 3.4e38f, 3.4e38f};
    int   bk1[4]   = {0, 0, 0, 0};
    int   bk2[4]   = {0, 0, 0, 0};

    // register double-buffer of B-fragments (1-tile lookahead, no barriers)
    f16x8 cbh0 = ehp[fb + lane],       cbh1 = ehp[fb + 64 + lane];
    f16x8 cbl0 = elp[fb + lane],       cbl1 = elp[fb + 64 + lane];

#pragma unroll 1
    for (int ct = 0; ct < 16; ++ct) {
        f16x8 nbh0, nbh1, nbl0, nbl1;
        if (ct < 15) {                    // issue next tile's loads early
            const int o = fb + (ct * 2 + 2) * 64 + lane;
            nbh0 = ehp[o]; nbh1 = ehp[o + 64];
            nbl0 = elp[o]; nbl1 = elp[o + 64];
        }
        f32x4 acch = {0.f, 0.f, 0.f, 0.f};
        f32x4 accm = {0.f, 0.f, 0.f, 0.f};
        acch = __builtin_amdgcn_mfma_f32_16x16x32_f16(ah0, cbh0, acch, 0, 0, 0);
        acch = __builtin_amdgcn_mfma_f32_16x16x32_f16(ah1, cbh1, acch, 0, 0, 0);
        accm = __builtin_amdgcn_mfma_f32_16x16x32_f16(al0, cbh0, accm, 0, 0, 0);
        accm = __builtin_amdgcn_mfma_f32_16x16x32_f16(al1, cbh1, accm, 0, 0, 0);
        accm = __builtin_amdgcn_mfma_f32_16x16x32_f16(ah0, cbl0, accm, 0, 0, 0);
        accm = __builtin_amdgcn_mfma_f32_16x16x32_f16(ah1, cbl1, accm, 0, 0, 0);
        const int   kk  = kb0 + ct * 16 + (lane & 15);   // C/D col = lane&15
        const float enk = enS[kk];
#pragma unroll
        for (int j = 0; j < 4; ++j) {
            // zn-free approx score: en[k] - 2*dot (ordering-equivalent)
            float dot = fmaf(accm[j], INV_ELS, acch[j]);
            float sc  = fmaf(-2.0f, dot, enk);
            bool  c1  = sc < best[j];
            bool  c2  = sc < best2[j];
            bk2[j]    = c1 ? bk1[j] : (c2 ? kk : bk2[j]);
            best2[j]  = fminf(best2[j], fmaxf(sc, best[j]));
            bk1[j]    = c1 ? kk : bk1[j];
            best[j]   = fminf(sc, best[j]);
        }
        if (ct < 15) { cbh0 = nbh0; cbh1 = nbh1; cbl0 = nbl0; cbl1 = nbl1; }
    }

    // top-2 (with indices) merge across the 16 lanes sharing each vector row
#pragma unroll
    for (int m = 1; m <= 8; m <<= 1) {
#pragma unroll
        for (int j = 0; j < 4; ++j) {
            float qb  = __shfl_xor(best[j],  m);
            int   qk  = __shfl_xor(bk1[j],   m);
            float q2  = __shfl_xor(best2[j], m);
            int   qk2 = __shfl_xor(bk2[j],   m);
            bool  t1  = (qb < best[j]) || (qb == best[j] && qk < bk1[j]);
            float lb  = t1 ? best[j] : qb;      // losing first
            int   lk  = t1 ? bk1[j]  : qk;
            float nb  = t1 ? qb : best[j];      // winning first
            int   nk  = t1 ? qk : bk1[j];
            bool  ta  = (best2[j] < q2) || (best2[j] == q2 && bk2[j] < qk2);
            float sb  = ta ? best2[j] : q2;
            int   sk  = ta ? bk2[j]   : qk2;
            bool  tb  = (lb < sb) || (lb == sb && lk < sk);
            best2[j]  = tb ? lb : sb;
            bk2[j]    = tb ? lk : sk;
            best[j]   = nb;
            bk1[j]    = nk;
        }
    }
    {
        const int j = lane & 15;
        if (j < 4) {
            const int v = vb + g4 * 4 + j;
            sdf1[half][v] = best[j];
            sdf2[half][v] = best2[j];
            k1a[half][v]  = bk1[j];
            k2a[half][v]  = bk2[j];
        }
    }
    __syncthreads();

    // merge the two code-halves per vector (lex (dist,k): half-0 ks lower)
    if (tid < VPB) {
        const float a1 = sdf1[0][tid]; const int ka1 = k1a[0][tid];
        const float a2 = sdf2[0][tid]; const int ka2 = k2a[0][tid];
        const float c1 = sdf1[1][tid]; const int kc1 = k1a[1][tid];
        const float c2 = sdf2[1][tid]; const int kc2 = k2a[1][tid];
        const bool afirst = (a1 < c1) || (a1 == c1 && ka1 < kc1);
        const float f1 = afirst ? a1 : c1;  const int fk1 = afirst ? ka1 : kc1;
        const float u  = afirst ? a2 : c2;  const int uk  = afirst ? ka2 : kc2; // winner's 2nd
        const float w  = afirst ? c1 : a1;  const int wk  = afirst ? kc1 : ka1; // loser's 1st
        const bool usec = (u < w) || (u == w && uk < wk);
        cand[tid][0] = fk1;               sdfm[tid][0] = f1;
        cand[tid][1] = usec ? uk : wk;    sdfm[tid][1] = usec ? u : w;
    }
    __syncthreads();

    // conditional exact rescore (reference-exact chain; zn computed inline)
    if (tid < 2 * VPB) {
        const int v = tid >> 1, cc = tid & 1;
        float res = sdfm[v][cc];
        if (sdfm[v][1] - sdfm[v][0] <= GAP_THR) {
            const int k = cand[v][cc];
            const float* xr = x + xbase + v * DIM;
            const float* er = ws_ro + WS_EMBT + k * 64;
            float zn = 0.f, dot = 0.f;
#pragma unroll
            for (int d = 0; d < DIM; ++d) {
                float xv = xr[d];
                zn  = fmaf(xv, xv, zn);
                dot = fmaf(xv, er[d], dot);
            }
            res = fmaf(-2.0f, dot, zn + enS[k]);
        }
        exd[v][cc] = res;
    }
    __syncthreads();
    if (tid < VPB) {
        const int k0 = cand[tid][0], k1 = cand[tid][1];
        const float d0 = exd[tid][0], d1 = exd[tid][1];
        const bool take2 = (d1 < d0) || (d1 == d0 && k1 < k0);
        bksel[tid] = take2 ? k1 : k0;
    }
    __syncthreads();

    // epilogue: thread -> (vector v16, dim-block j8); q from embT rows
    const int v16 = tid >> 3;             // 0..63
    const int j8  = (tid & 7) * 8;
    const int bk  = bksel[v16];
    const int gvec = blockIdx.x * VPB + v16;
    const float*  xg  = x + (size_t)gvec * DIM + j8;
    float*        og  = out + (size_t)gvec * DIM + j8;
    const float4* et4 = (const float4*)(ws_ro + WS_EMBT + bk * 64);

    float lossLocal = 0.f;
#pragma unroll
    for (int c = 0; c < 2; ++c) {
        float4 q  = et4[(tid & 7) * 2 + c];
        *(float4*)(og + c * 4) = q;
        float4 xa = *(const float4*)(xg + c * 4);
        float a;
        a = q.x - xa.x; lossLocal = fmaf(a, a, lossLocal);
        a = q.y - xa.y; lossLocal = fmaf(a, a, lossLocal);
        a = q.z - xa.z; lossLocal = fmaf(a, a, lossLocal);
        a = q.w - xa.w; lossLocal = fmaf(a, a, lossLocal);
    }

    // block-reduce loss -> one partial store per block (no atomics)
#pragma unroll
    for (int off = 32; off; off >>= 1) lossLocal += __shfl_down(lossLocal, off, 64);
    if (lane == 0) swl[wid] = lossLocal;
    __syncthreads();
    if (tid == 0) {
        float s = 0.f;
#pragma unroll
        for (int i = 0; i < 8; ++i) s += swl[i];
        part[WS_PART + blockIdx.x] = s;
    }
}

// Finish: reduce 1024 per-block partials, write the loss element.
__global__ __launch_bounds__(256, 1) void finish_kernel(const float* __restrict__ part,
                                                        float* __restrict__ out) {
    __shared__ float sw[4];
    const int tid = threadIdx.x, lane = tid & 63, wid = tid >> 6;
    float s = part[WS_PART + tid]       + part[WS_PART + tid + 256]
            + part[WS_PART + tid + 512] + part[WS_PART + tid + 768];
#pragma unroll
    for (int off = 32; off; off >>= 1) s += __shfl_down(s, off, 64);
    if (lane == 0) sw[wid] = s;
    __syncthreads();
    if (tid == 0) {
        float total = sw[0] + sw[1] + sw[2] + sw[3];
        out[(size_t)NVEC * DIM] = 2.0f * total / (float)((size_t)NVEC * DIM);
    }
}

extern "C" void kernel_launch(void* const* d_in, const int* in_sizes, int n_in,
                              void* d_out, int out_size, void* d_ws, size_t ws_size,
                              hipStream_t stream) {
    const float* x   = (const float*)d_in[0];
    const float* emb = (const float*)d_in[1];
    float* out = (float*)d_out;
    float* ws  = (float*)d_ws;

    prep_kernel<<<dim3(17), dim3(512), 0, stream>>>(emb, ws);
    vq_kernel<<<dim3(NBLK), dim3(512), 0, stream>>>(x, ws, out, ws);
    finish_kernel<<<dim3(1), dim3(256), 0, stream>>>(ws, out);
}

// Round 13
// 48.639 us; speedup vs baseline: 4.1211x; 1.2457x over previous
//
#include <hip/hip_runtime.h>

// B*H*W = 65536 vectors, dim 64, 512 codes
#define NVEC 65536
#define DIM 64
#define KCODES 512
#define VPB 128       // vectors per block
#define NBLK 512      // NVEC / VPB
#define ELS 2048.0f   // residual pre-scale (avoids fp16 denormals)
#define INV_ELS (1.0f / 2048.0f)
#define GAP_THR 2e-4f // rescore guard: >> max split-fp16 ordering error (~1.5e-5)

typedef _Float16 f16x8 __attribute__((ext_vector_type(8)));
typedef float    f32x4 __attribute__((ext_vector_type(4)));

// ws layout (floats):
#define WS_EN   4                   // [4..516) codebook norms
#define WS_EH   1024                // [1024..17408) hi fp16 B-fragments (pre-scaled by -2)
#define WS_EL   (1024 + 16384)      // [17408..33792) residual fp16 B-fragments (pre-scaled by -2*ELS)
#define WS_PART 33792               // [33792..34304) per-block loss partials (512)
#define WS_EMBT 34816               // [34816..67584) embT[k][d]

// Prep (17 blocks x 512): b=0 exact norms; b=1..8 MFMA B-fragments with the
// -2 distance factor folded in (exact: *2 is lossless in fp16); b=9..16
// transpose emb -> embT[k][d] via LDS tile.
__global__ __launch_bounds__(512, 1) void prep_kernel(const float* __restrict__ emb,
                                                      float* __restrict__ ws) {
    const int tid = threadIdx.x;
    const int b   = blockIdx.x;
    if (b == 0) {
        float s = 0.f;
#pragma unroll
        for (int d = 0; d < DIM; ++d) { float v = emb[d * KCODES + tid]; s = fmaf(v, v, s); }
        ws[WS_EN + tid] = s;
    } else if (b <= 8) {
        const int fl = (b - 1) * 512 + tid;            // fragment-lane id, 0..4095
        const int ct = fl >> 7, s5 = (fl >> 6) & 1, l = fl & 63;
        const int k  = ct * 16 + (l & 15);             // B col
        const int d0 = s5 * 32 + (l >> 4) * 8;         // B k-rows (d)
        f16x8 eh, el;
#pragma unroll
        for (int e = 0; e < 8; ++e) {
            float v = emb[(d0 + e) * KCODES + k];
            _Float16 h = (_Float16)v;
            _Float16 l16 = (_Float16)((v - (float)h) * ELS);
            eh[e] = -(h + h);      // -2*h, exact
            el[e] = -(l16 + l16);  // -2*l, exact
        }
        ((f16x8*)(ws + WS_EH))[fl] = eh;
        ((f16x8*)(ws + WS_EL))[fl] = el;
    } else {
        __shared__ float tl[64][65];
        const int kt = b - 9;          // k-tile 0..7
        const int r  = tid >> 3;       // 0..63
        const int g  = tid & 7;
#pragma unroll
        for (int i = 0; i < 8; ++i)
            tl[r][g * 8 + i] = emb[r * KCODES + kt * 64 + g * 8 + i];
        __syncthreads();
#pragma unroll
        for (int i = 0; i < 8; ++i)
            ws[WS_EMBT + (kt * 64 + r) * 64 + g * 8 + i] = tl[g * 8 + i][r];
    }
}

// Main: 256 thr = 4 waves, 128 vectors/block, grid 512 = 2 blocks/CU.
// Each wave owns M=32 vectors (two 16-row A-tile sets) and scans all 512
// codes: per-CU fragment traffic HALVED vs R9 (the measured binder), MFMA
// total unchanged (12 per 16-code tile). C-operand initialized to en[k] and
// -2 folded into B at prep -> approx score = ONE fmaf per code. Top-2 via
// med3 + explicit k tracking; 16-lane lex merge; exact fp32 rescore when
// approx gap <= GAP_THR; embT epilogue; no atomics.
__global__ __launch_bounds__(256, 2) void vq_kernel(const float* __restrict__ x,
                                                    const float* __restrict__ ws_ro,
                                                    float* __restrict__ out,
                                                    float* __restrict__ part) {
    __shared__ f16x8 zhS[VPB][8];   // [v][u], u = (d>>3) ^ (v&7)  (bank swizzle)
    __shared__ f16x8 zlS[VPB][8];
    __shared__ float enS[KCODES];
    __shared__ int   cand[VPB][2];
    __shared__ float sdfm[VPB][2];
    __shared__ float exd[VPB][2];
    __shared__ int   bksel[VPB];
    __shared__ float swl[4];

    const int tid  = threadIdx.x;
    const int wid  = tid >> 6;            // 0..3
    const int lane = tid & 63;
    const size_t xbase = (size_t)blockIdx.x * VPB * DIM;

    enS[tid]       = ws_ro[WS_EN + tid];
    enS[tid + 256] = ws_ro[WS_EN + tid + 256];

    // x-block -> fp16 hi + scaled residual into swizzled LDS (2 thr/vector)
    {
        const int v     = tid >> 1;       // 0..127
        const int dbase = (tid & 1) * 32;
        const float4* xp4 = (const float4*)(x + xbase + v * DIM + dbase);
#pragma unroll
        for (int g = 0; g < 4; ++g) {
            float4 a = xp4[g * 2];
            float4 b = xp4[g * 2 + 1];
            float t0[8] = {a.x, a.y, a.z, a.w, b.x, b.y, b.z, b.w};
            f16x8 h0, l0;
#pragma unroll
            for (int i = 0; i < 8; ++i) {
                _Float16 h = (_Float16)t0[i];
                h0[i] = h;
                l0[i] = (_Float16)((t0[i] - (float)h) * ELS);
            }
            const int u = ((dbase >> 3) + g) ^ (v & 7);
            zhS[v][u] = h0;
            zlS[v][u] = l0;
        }
    }
    __syncthreads();

    // A-fragments for TWO 16-row tiles: rows vb..vb+15 and vb+16..vb+31
    const int vb = wid * 32;
    const int r  = lane & 15;
    const int g4 = lane >> 4;
    const int vA0 = vb + r,      sw0 = vA0 & 7;
    const int vA1 = vb + 16 + r, sw1 = vA1 & 7;
    f16x8 ah0_0 = zhS[vA0][(g4)     ^ sw0];
    f16x8 ah1_0 = zhS[vA0][(4 + g4) ^ sw0];
    f16x8 al0_0 = zlS[vA0][(g4)     ^ sw0];
    f16x8 al1_0 = zlS[vA0][(4 + g4) ^ sw0];
    f16x8 ah0_1 = zhS[vA1][(g4)     ^ sw1];
    f16x8 ah1_1 = zhS[vA1][(4 + g4) ^ sw1];
    f16x8 al0_1 = zlS[vA1][(g4)     ^ sw1];
    f16x8 al1_1 = zlS[vA1][(4 + g4) ^ sw1];

    const f16x8* ehp = (const f16x8*)(ws_ro + WS_EH);
    const f16x8* elp = (const f16x8*)(ws_ro + WS_EL);

    float best[8], best2[8];
    int   bk1[8], bk2[8];
#pragma unroll
    for (int s = 0; s < 8; ++s) {
        best[s] = 3.4e38f; best2[s] = 3.4e38f; bk1[s] = 0; bk2[s] = 0;
    }

    // register double-buffer of B-fragments (1-tile lookahead, no barriers)
    f16x8 cbh0 = ehp[lane], cbh1 = ehp[64 + lane];
    f16x8 cbl0 = elp[lane], cbl1 = elp[64 + lane];
    int kkv = r;                          // running code id for this lane

#pragma unroll 1
    for (int ct = 0; ct < 32; ++ct) {
        f16x8 nbh0, nbh1, nbl0, nbl1;
        if (ct < 31) {                    // issue next tile's loads early
            const int o = (ct * 2 + 2) * 64 + lane;
            nbh0 = ehp[o]; nbh1 = ehp[o + 64];
            nbl0 = elp[o]; nbl1 = elp[o + 64];
        }
        const float enk = enS[kkv];
        f32x4 acch0 = {enk, enk, enk, enk};
        f32x4 accm0 = {0.f, 0.f, 0.f, 0.f};
        f32x4 acch1 = {enk, enk, enk, enk};
        f32x4 accm1 = {0.f, 0.f, 0.f, 0.f};
        acch0 = __builtin_amdgcn_mfma_f32_16x16x32_f16(ah0_0, cbh0, acch0, 0, 0, 0);
        acch0 = __builtin_amdgcn_mfma_f32_16x16x32_f16(ah1_0, cbh1, acch0, 0, 0, 0);
        accm0 = __builtin_amdgcn_mfma_f32_16x16x32_f16(al0_0, cbh0, accm0, 0, 0, 0);
        accm0 = __builtin_amdgcn_mfma_f32_16x16x32_f16(al1_0, cbh1, accm0, 0, 0, 0);
        accm0 = __builtin_amdgcn_mfma_f32_16x16x32_f16(ah0_0, cbl0, accm0, 0, 0, 0);
        accm0 = __builtin_amdgcn_mfma_f32_16x16x32_f16(ah1_0, cbl1, accm0, 0, 0, 0);
        acch1 = __builtin_amdgcn_mfma_f32_16x16x32_f16(ah0_1, cbh0, acch1, 0, 0, 0);
        acch1 = __builtin_amdgcn_mfma_f32_16x16x32_f16(ah1_1, cbh1, acch1, 0, 0, 0);
        accm1 = __builtin_amdgcn_mfma_f32_16x16x32_f16(al0_1, cbh0, accm1, 0, 0, 0);
        accm1 = __builtin_amdgcn_mfma_f32_16x16x32_f16(al1_1, cbh1, accm1, 0, 0, 0);
        accm1 = __builtin_amdgcn_mfma_f32_16x16x32_f16(ah0_1, cbl0, accm1, 0, 0, 0);
        accm1 = __builtin_amdgcn_mfma_f32_16x16x32_f16(ah1_1, cbl1, accm1, 0, 0, 0);
        // sc = en[k] - 2*dot (en in C-init, -2 in B):  ONE fmaf per code
#define UPD(S, ACCH, ACCM, J) { \
        float sc = fmaf(ACCM[J], INV_ELS, ACCH[J]); \
        bool c1 = sc < best[S]; \
        bool c2 = sc < best2[S]; \
        bk2[S]  = c1 ? bk1[S] : (c2 ? kkv : bk2[S]); \
        bk1[S]  = c1 ? kkv : bk1[S]; \
        best2[S] = __builtin_amdgcn_fmed3f(sc, best[S], best2[S]); \
        best[S]  = fminf(sc, best[S]); }
        UPD(0, acch0, accm0, 0) UPD(1, acch0, accm0, 1)
        UPD(2, acch0, accm0, 2) UPD(3, acch0, accm0, 3)
        UPD(4, acch1, accm1, 0) UPD(5, acch1, accm1, 1)
        UPD(6, acch1, accm1, 2) UPD(7, acch1, accm1, 3)
#undef UPD
        kkv += 16;
        if (ct < 31) { cbh0 = nbh0; cbh1 = nbh1; cbl0 = nbl0; cbl1 = nbl1; }
    }

    // top-2 (with indices) merge across the 16 lanes sharing each vector row
#pragma unroll
    for (int m = 1; m <= 8; m <<= 1) {
#pragma unroll
        for (int s = 0; s < 8; ++s) {
            float qb  = __shfl_xor(best[s],  m);
            int   qk  = __shfl_xor(bk1[s],   m);
            float q2  = __shfl_xor(best2[s], m);
            int   qk2 = __shfl_xor(bk2[s],   m);
            bool  t1  = (qb < best[s]) || (qb == best[s] && qk < bk1[s]);
            float lb  = t1 ? best[s] : qb;      // losing first
            int   lk  = t1 ? bk1[s]  : qk;
            float nb  = t1 ? qb : best[s];      // winning first
            int   nk  = t1 ? qk : bk1[s];
            bool  ta  = (best2[s] < q2) || (best2[s] == q2 && bk2[s] < qk2);
            float sb  = ta ? best2[s] : q2;
            int   sk  = ta ? bk2[s]   : qk2;
            bool  tb  = (lb < sb) || (lb == sb && lk < sk);
            best2[s]  = tb ? lb : sb;
            bk2[s]    = tb ? lk : sk;
            best[s]   = nb;
            bk1[s]    = nk;
        }
    }
    {
        const int j = lane & 15;
        if (j < 4) {                      // static-index extraction (rule #20)
#define PICK4F(A, J) ((J) == 0 ? A[0] : (J) == 1 ? A[1] : (J) == 2 ? A[2] : A[3])
#define PICK4I(A, J) ((J) == 0 ? A[0] : (J) == 1 ? A[1] : (J) == 2 ? A[2] : A[3])
            const int v0 = vb + g4 * 4 + j;
            sdfm[v0][0] = PICK4F(best,  j);  sdfm[v0][1] = PICK4F(best2, j);
            cand[v0][0] = PICK4I(bk1,   j);  cand[v0][1] = PICK4I(bk2,   j);
            const int v1 = vb + 16 + g4 * 4 + j;
            sdfm[v1][0] = PICK4F((best + 4),  j);  sdfm[v1][1] = PICK4F((best2 + 4), j);
            cand[v1][0] = PICK4I((bk1 + 4),   j);  cand[v1][1] = PICK4I((bk2 + 4),   j);
#undef PICK4F
#undef PICK4I
        }
    }
    __syncthreads();

    // conditional exact rescore (reference-exact chain; zn computed inline)
    {
        const int v = tid >> 1, cc = tid & 1;
        float res = sdfm[v][cc];
        if (sdfm[v][1] - sdfm[v][0] <= GAP_THR) {
            const int k = cand[v][cc];
            const float* xr = x + xbase + v * DIM;
            const float* er = ws_ro + WS_EMBT + k * 64;
            float zn = 0.f, dot = 0.f;
#pragma unroll
            for (int d = 0; d < DIM; ++d) {
                float xv = xr[d];
                zn  = fmaf(xv, xv, zn);
                dot = fmaf(xv, er[d], dot);
            }
            res = fmaf(-2.0f, dot, zn + enS[k]);
        }
        exd[v][cc] = res;
    }
    __syncthreads();
    if (tid < VPB) {
        const int k0 = cand[tid][0], k1 = cand[tid][1];
        const float d0 = exd[tid][0], d1 = exd[tid][1];
        const bool take2 = (d1 < d0) || (d1 == d0 && k1 < k0);
        bksel[tid] = take2 ? k1 : k0;
    }
    __syncthreads();

    // epilogue: thread -> (vector tid>>1, half (tid&1)*32); q from embT rows
    const int v16  = tid >> 1;            // 0..127
    const int hoff = (tid & 1) * 8;       // float4 offset within the row
    const int bk   = bksel[v16];
    const int gvec = blockIdx.x * VPB + v16;
    const float4* xg4 = (const float4*)(x + (size_t)gvec * DIM) + hoff;
    float4*       og4 = (float4*)(out + (size_t)gvec * DIM) + hoff;
    const float4* et4 = (const float4*)(ws_ro + WS_EMBT + bk * 64) + hoff;

    float lossLocal = 0.f;
#pragma unroll
    for (int c = 0; c < 8; ++c) {
        float4 q  = et4[c];
        og4[c] = q;
        float4 xa = xg4[c];
        float a;
        a = q.x - xa.x; lossLocal = fmaf(a, a, lossLocal);
        a = q.y - xa.y; lossLocal = fmaf(a, a, lossLocal);
        a = q.z - xa.z; lossLocal = fmaf(a, a, lossLocal);
        a = q.w - xa.w; lossLocal = fmaf(a, a, lossLocal);
    }

    // block-reduce loss -> one partial store per block (no atomics)
#pragma unroll
    for (int off = 32; off; off >>= 1) lossLocal += __shfl_down(lossLocal, off, 64);
    if (lane == 0) swl[wid] = lossLocal;
    __syncthreads();
    if (tid == 0)
        part[WS_PART + blockIdx.x] = swl[0] + swl[1] + swl[2] + swl[3];
}

// Finish: reduce 512 per-block partials, write the loss element.
__global__ __launch_bounds__(256, 1) void finish_kernel(const float* __restrict__ part,
                                                        float* __restrict__ out) {
    __shared__ float sw[4];
    const int tid = threadIdx.x, lane = tid & 63, wid = tid >> 6;
    float s = part[WS_PART + tid] + part[WS_PART + tid + 256];
#pragma unroll
    for (int off = 32; off; off >>= 1) s += __shfl_down(s, off, 64);
    if (lane == 0) sw[wid] = s;
    __syncthreads();
    if (tid == 0) {
        float total = sw[0] + sw[1] + sw[2] + sw[3];
        out[(size_t)NVEC * DIM] = 2.0f * total / (float)((size_t)NVEC * DIM);
    }
}

extern "C" void kernel_launch(void* const* d_in, const int* in_sizes, int n_in,
                              void* d_out, int out_size, void* d_ws, size_t ws_size,
                              hipStream_t stream) {
    const float* x   = (const float*)d_in[0];
    const float* emb = (const float*)d_in[1];
    float* out = (float*)d_out;
    float* ws  = (float*)d_ws;

    prep_kernel<<<dim3(17), dim3(512), 0, stream>>>(emb, ws);
    vq_kernel<<<dim3(NBLK), dim3(256), 0, stream>>>(x, ws, out, ws);
    finish_kernel<<<dim3(1), dim3(256), 0, stream>>>(ws, out);
}

// Round 14
// 45.440 us; speedup vs baseline: 4.4113x; 1.0704x over previous
//
#include <hip/hip_runtime.h>

// B*H*W = 65536 vectors, dim 64, 512 codes
#define NVEC 65536
#define DIM 64
#define KCODES 512
#define VPB 128       // vectors per block
#define NBLK 512      // NVEC / VPB
#define ELS 2048.0f   // residual pre-scale (avoids fp16 denormals)
#define INV_ELS (1.0f / 2048.0f)
#define GAP_THR 2e-4f // rescore guard: >> max split-fp16 ordering error (~1.5e-5)

typedef _Float16 f16x8 __attribute__((ext_vector_type(8)));
typedef float    f32x4 __attribute__((ext_vector_type(4)));

// ws layout (floats):
#define WS_EN   4                   // [4..516) codebook norms
#define WS_EH   1024                // [1024..17408) hi fp16 B-fragments (pre-scaled by -2)
#define WS_EL   (1024 + 16384)      // [17408..33792) residual fp16 B-fragments (pre-scaled by -2*ELS)
#define WS_PART 33792               // [33792..34304) per-block loss partials (512)
#define WS_EMBT 34816               // [34816..67584) embT[k][d]

// Prep (17 blocks x 512): b=0 exact norms; b=1..8 MFMA B-fragments with the
// -2 factor folded in (exact: *2 lossless in fp16); b=9..16 emb -> embT.
__global__ __launch_bounds__(512, 1) void prep_kernel(const float* __restrict__ emb,
                                                      float* __restrict__ ws) {
    const int tid = threadIdx.x;
    const int b   = blockIdx.x;
    if (b == 0) {
        float s = 0.f;
#pragma unroll
        for (int d = 0; d < DIM; ++d) { float v = emb[d * KCODES + tid]; s = fmaf(v, v, s); }
        ws[WS_EN + tid] = s;
    } else if (b <= 8) {
        const int fl = (b - 1) * 512 + tid;            // fragment-lane id, 0..4095
        const int ct = fl >> 7, s5 = (fl >> 6) & 1, l = fl & 63;
        const int k  = ct * 16 + (l & 15);             // B col
        const int d0 = s5 * 32 + (l >> 4) * 8;         // B k-rows (d)
        f16x8 eh, el;
#pragma unroll
        for (int e = 0; e < 8; ++e) {
            float v = emb[(d0 + e) * KCODES + k];
            _Float16 h = (_Float16)v;
            _Float16 l16 = (_Float16)((v - (float)h) * ELS);
            eh[e] = -(h + h);      // -2*h, exact
            el[e] = -(l16 + l16);  // -2*l, exact
        }
        ((f16x8*)(ws + WS_EH))[fl] = eh;
        ((f16x8*)(ws + WS_EL))[fl] = el;
    } else {
        __shared__ float tl[64][65];
        const int kt = b - 9;          // k-tile 0..7
        const int r  = tid >> 3;       // 0..63
        const int g  = tid & 7;
#pragma unroll
        for (int i = 0; i < 8; ++i)
            tl[r][g * 8 + i] = emb[r * KCODES + kt * 64 + g * 8 + i];
        __syncthreads();
#pragma unroll
        for (int i = 0; i < 8; ++i)
            ws[WS_EMBT + (kt * 64 + r) * 64 + g * 8 + i] = tl[g * 8 + i][r];
    }
}

// Main: 512 thr = 8 waves, VPB=128, grid 512 -> 4096 waves = 4 waves/SIMD
// (R9's proven residency). Each wave owns M=16 vectors, scans all 512 codes.
// Slim scoring (R13-proven): en[k] in the MFMA C-operand, -2 folded into B
// -> approx score = ONE fmaf/code; med3 top-2. B-fragments prefetched 2
// tiles deep (load-to-use ~2 iterations > L2 latency). Lex (dist,k) 16-lane
// merge; exact fp32 rescore when gap <= GAP_THR; embT epilogue; no atomics.
__global__ __launch_bounds__(512, 2) void vq_kernel(const float* __restrict__ x,
                                                    const float* __restrict__ ws_ro,
                                                    float* __restrict__ out,
                                                    float* __restrict__ part) {
    __shared__ f16x8 zhS[VPB][8];   // [v][u], u = (d>>3) ^ (v&7)  (bank swizzle)
    __shared__ f16x8 zlS[VPB][8];
    __shared__ float enS[KCODES];
    __shared__ int   cand[VPB][2];
    __shared__ float sdfm[VPB][2];
    __shared__ float exd[VPB][2];
    __shared__ int   bksel[VPB];
    __shared__ float swl[8];

    const int tid  = threadIdx.x;
    const int wid  = tid >> 6;            // 0..7
    const int lane = tid & 63;
    const size_t xbase = (size_t)blockIdx.x * VPB * DIM;

    enS[tid] = ws_ro[WS_EN + tid];        // 512 threads, one code each

    // x-block -> fp16 hi + scaled residual into swizzled LDS (4 thr/vector)
    {
        const int v  = tid >> 2;          // 0..127
        const int d0 = (tid & 3) * 16;
        const float* xp = x + xbase + v * DIM + d0;
        float4 a = *(const float4*)(xp);
        float4 b = *(const float4*)(xp + 4);
        float4 c = *(const float4*)(xp + 8);
        float4 e = *(const float4*)(xp + 12);
        float t0[8] = {a.x, a.y, a.z, a.w, b.x, b.y, b.z, b.w};
        float t1[8] = {c.x, c.y, c.z, c.w, e.x, e.y, e.z, e.w};
        f16x8 h0, l0, h1, l1;
#pragma unroll
        for (int i = 0; i < 8; ++i) {
            _Float16 h = (_Float16)t0[i]; h0[i] = h; l0[i] = (_Float16)((t0[i] - (float)h) * ELS);
            _Float16 g = (_Float16)t1[i]; h1[i] = g; l1[i] = (_Float16)((t1[i] - (float)g) * ELS);
        }
        const int u0 = ((d0 >> 3))     ^ (v & 7);
        const int u1 = ((d0 >> 3) + 1) ^ (v & 7);
        zhS[v][u0] = h0; zhS[v][u1] = h1;
        zlS[v][u0] = l0; zlS[v][u1] = l1;
    }
    __syncthreads();

    // A-fragments: row = lane&15 (vector), k = (lane>>4)*8 + e (+32 for 2nd)
    const int vb = wid * 16;
    const int r  = lane & 15;
    const int g4 = lane >> 4;
    const int vA = vb + r;
    const int sw = vA & 7;
    f16x8 ah0 = zhS[vA][(g4)     ^ sw];
    f16x8 ah1 = zhS[vA][(4 + g4) ^ sw];
    f16x8 al0 = zlS[vA][(g4)     ^ sw];
    f16x8 al1 = zlS[vA][(4 + g4) ^ sw];

    const f16x8* ehp = (const f16x8*)(ws_ro + WS_EH);
    const f16x8* elp = (const f16x8*)(ws_ro + WS_EL);

    float best[4]  = {3.4e38f, 3.4e38f, 3.4e38f, 3.4e38f};
    float best2[4] = {3.4e38f, 3.4e38f, 3.4e38f, 3.4e38f};
    int   bk1[4]   = {0, 0, 0, 0};
    int   bk2[4]   = {0, 0, 0, 0};

    // 2-deep register pipeline of B-fragments (tiles t and t+1 in flight)
    f16x8 Ah0 = ehp[lane],        Ah1 = ehp[64 + lane];
    f16x8 Al0 = elp[lane],        Al1 = elp[64 + lane];
    f16x8 Bh0 = ehp[128 + lane],  Bh1 = ehp[192 + lane];
    f16x8 Bl0 = elp[128 + lane],  Bl1 = elp[192 + lane];

#define COMPUTE(T, H0, H1, L0, L1) { \
        const float enk = enS[(T) * 16 + r]; \
        f32x4 acch = {enk, enk, enk, enk}; \
        f32x4 accm = {0.f, 0.f, 0.f, 0.f}; \
        acch = __builtin_amdgcn_mfma_f32_16x16x32_f16(ah0, H0, acch, 0, 0, 0); \
        acch = __builtin_amdgcn_mfma_f32_16x16x32_f16(ah1, H1, acch, 0, 0, 0); \
        accm = __builtin_amdgcn_mfma_f32_16x16x32_f16(al0, H0, accm, 0, 0, 0); \
        accm = __builtin_amdgcn_mfma_f32_16x16x32_f16(al1, H1, accm, 0, 0, 0); \
        accm = __builtin_amdgcn_mfma_f32_16x16x32_f16(ah0, L0, accm, 0, 0, 0); \
        accm = __builtin_amdgcn_mfma_f32_16x16x32_f16(ah1, L1, accm, 0, 0, 0); \
        const int kk = (T) * 16 + r; \
        _Pragma("unroll") \
        for (int j = 0; j < 4; ++j) { \
            float sc = fmaf(accm[j], INV_ELS, acch[j]); \
            bool c1 = sc < best[j]; \
            bool c2 = sc < best2[j]; \
            bk2[j]   = c1 ? bk1[j] : (c2 ? kk : bk2[j]); \
            bk1[j]   = c1 ? kk : bk1[j]; \
            best2[j] = __builtin_amdgcn_fmed3f(sc, best[j], best2[j]); \
            best[j]  = fminf(sc, best[j]); \
        } }

#pragma unroll 1
    for (int ct = 0; ct < 32; ct += 2) {
        f16x8 nAh0, nAh1, nAl0, nAl1, nBh0, nBh1, nBl0, nBl1;
        if (ct < 30) {                    // issue tile ct+2 loads early
            const int o = (ct + 2) * 128 + lane;
            nAh0 = ehp[o]; nAh1 = ehp[o + 64];
            nAl0 = elp[o]; nAl1 = elp[o + 64];
        }
        COMPUTE(ct, Ah0, Ah1, Al0, Al1)
        if (ct < 30) {                    // issue tile ct+3 loads
            const int o = (ct + 3) * 128 + lane;
            nBh0 = ehp[o]; nBh1 = ehp[o + 64];
            nBl0 = elp[o]; nBl1 = elp[o + 64];
        }
        COMPUTE(ct + 1, Bh0, Bh1, Bl0, Bl1)
        if (ct < 30) {
            Ah0 = nAh0; Ah1 = nAh1; Al0 = nAl0; Al1 = nAl1;
            Bh0 = nBh0; Bh1 = nBh1; Bl0 = nBl0; Bl1 = nBl1;
        }
    }
#undef COMPUTE

    // top-2 (with indices) merge across the 16 lanes sharing each vector row
#pragma unroll
    for (int m = 1; m <= 8; m <<= 1) {
#pragma unroll
        for (int j = 0; j < 4; ++j) {
            float qb  = __shfl_xor(best[j],  m);
            int   qk  = __shfl_xor(bk1[j],   m);
            float q2  = __shfl_xor(best2[j], m);
            int   qk2 = __shfl_xor(bk2[j],   m);
            bool  t1  = (qb < best[j]) || (qb == best[j] && qk < bk1[j]);
            float lb  = t1 ? best[j] : qb;      // losing first
            int   lk  = t1 ? bk1[j]  : qk;
            float nb  = t1 ? qb : best[j];      // winning first
            int   nk  = t1 ? qk : bk1[j];
            bool  ta  = (best2[j] < q2) || (best2[j] == q2 && bk2[j] < qk2);
            float sb  = ta ? best2[j] : q2;
            int   sk  = ta ? bk2[j]   : qk2;
            bool  tb  = (lb < sb) || (lb == sb && lk < sk);
            best2[j]  = tb ? lb : sb;
            bk2[j]    = tb ? lk : sk;
            best[j]   = nb;
            bk1[j]    = nk;
        }
    }
    {
        const int j = lane & 15;
        if (j < 4) {                      // static-index extraction (rule #20)
            const int v = vb + g4 * 4 + j;
            sdfm[v][0] = j == 0 ? best[0]  : j == 1 ? best[1]  : j == 2 ? best[2]  : best[3];
            sdfm[v][1] = j == 0 ? best2[0] : j == 1 ? best2[1] : j == 2 ? best2[2] : best2[3];
            cand[v][0] = j == 0 ? bk1[0]   : j == 1 ? bk1[1]   : j == 2 ? bk1[2]   : bk1[3];
            cand[v][1] = j == 0 ? bk2[0]   : j == 1 ? bk2[1]   : j == 2 ? bk2[2]   : bk2[3];
        }
    }
    __syncthreads();

    // conditional exact rescore (reference-exact chain; zn computed inline)
    if (tid < 2 * VPB) {
        const int v = tid >> 1, cc = tid & 1;
        float res = sdfm[v][cc];
        if (sdfm[v][1] - sdfm[v][0] <= GAP_THR) {
            const int k = cand[v][cc];
            const float* xr = x + xbase + v * DIM;
            const float* er = ws_ro + WS_EMBT + k * 64;
            float zn = 0.f, dot = 0.f;
#pragma unroll
            for (int d = 0; d < DIM; ++d) {
                float xv = xr[d];
                zn  = fmaf(xv, xv, zn);
                dot = fmaf(xv, er[d], dot);
            }
            res = fmaf(-2.0f, dot, zn + enS[k]);
        }
        exd[v][cc] = res;
    }
    __syncthreads();
    if (tid < VPB) {
        const int k0 = cand[tid][0], k1 = cand[tid][1];
        const float d0 = exd[tid][0], d1 = exd[tid][1];
        const bool take2 = (d1 < d0) || (d1 == d0 && k1 < k0);
        bksel[tid] = take2 ? k1 : k0;
    }
    __syncthreads();

    // epilogue: thread -> (vector v16, dim-block j16); q from embT rows
    const int v16 = tid >> 2;             // 0..127
    const int j16 = (tid & 3) * 16;
    const int bk  = bksel[v16];
    const int gvec = blockIdx.x * VPB + v16;
    const float*  xg  = x + (size_t)gvec * DIM + j16;
    float*        og  = out + (size_t)gvec * DIM + j16;
    const float4* et4 = (const float4*)(ws_ro + WS_EMBT + bk * 64);

    float lossLocal = 0.f;
#pragma unroll
    for (int c = 0; c < 4; ++c) {
        float4 q  = et4[(tid & 3) * 4 + c];
        *(float4*)(og + c * 4) = q;
        float4 xa = *(const float4*)(xg + c * 4);
        float a;
        a = q.x - xa.x; lossLocal = fmaf(a, a, lossLocal);
        a = q.y - xa.y; lossLocal = fmaf(a, a, lossLocal);
        a = q.z - xa.z; lossLocal = fmaf(a, a, lossLocal);
        a = q.w - xa.w; lossLocal = fmaf(a, a, lossLocal);
    }

    // block-reduce loss -> one partial store per block (no atomics)
#pragma unroll
    for (int off = 32; off; off >>= 1) lossLocal += __shfl_down(lossLocal, off, 64);
    if (lane == 0) swl[wid] = lossLocal;
    __syncthreads();
    if (tid == 0) {
        float s = 0.f;
#pragma unroll
        for (int i = 0; i < 8; ++i) s += swl[i];
        part[WS_PART + blockIdx.x] = s;
    }
}

// Finish: reduce 512 per-block partials, write the loss element.
__global__ __launch_bounds__(256, 1) void finish_kernel(const float* __restrict__ part,
                                                        float* __restrict__ out) {
    __shared__ float sw[4];
    const int tid = threadIdx.x, lane = tid & 63, wid = tid >> 6;
    float s = part[WS_PART + tid] + part[WS_PART + tid + 256];
#pragma unroll
    for (int off = 32; off; off >>= 1) s += __shfl_down(s, off, 64);
    if (lane == 0) sw[wid] = s;
    __syncthreads();
    if (tid == 0) {
        float total = sw[0] + sw[1] + sw[2] + sw[3];
        out[(size_t)NVEC * DIM] = 2.0f * total / (float)((size_t)NVEC * DIM);
    }
}

extern "C" void kernel_launch(void* const* d_in, const int* in_sizes, int n_in,
                              void* d_out, int out_size, void* d_ws, size_t ws_size,
                              hipStream_t stream) {
    const float* x   = (const float*)d_in[0];
    const float* emb = (const float*)d_in[1];
    float* out = (float*)d_out;
    float* ws  = (float*)d_ws;

    prep_kernel<<<dim3(17), dim3(512), 0, stream>>>(emb, ws);
    vq_kernel<<<dim3(NBLK), dim3(512), 0, stream>>>(x, ws, out, ws);
    finish_kernel<<<dim3(1), dim3(256), 0, stream>>>(ws, out);
}

// Round 15
// 39.105 us; speedup vs baseline: 5.1259x; 1.1620x over previous
//
#include <hip/hip_runtime.h>

// B*H*W = 65536 vectors, dim 64, 512 codes
#define NVEC 65536
#define DIM 64
#define KCODES 512
#define VPB 128       // vectors per block
#define NBLK 512      // NVEC / VPB
#define ELS 2048.0f   // residual pre-scale (avoids fp16 denormals)
#define INV_ELS (1.0f / 2048.0f)
#define BIAS 8.0f     // score bias -> positive floats, uint-sortable
#define GAP_THR 2.5e-4f // rescore guard: > 2x (split-fp16 1.5e-5 + 5-bit mask 3e-5)

typedef _Float16 f16x8 __attribute__((ext_vector_type(8)));
typedef float    f32x4 __attribute__((ext_vector_type(4)));
typedef unsigned long long u64;

// ws layout (floats):
#define WS_EN   4                   // [4..516) codebook norms (exact)
#define WS_EH   1024                // [1024..17408) hi fp16 B-fragments (pre-scaled by -2)
#define WS_EL   (1024 + 16384)      // [17408..33792) residual fp16 B-fragments (pre-scaled by -2*ELS)
#define WS_PART 33792               // [33792..34304) per-block loss partials (512)
#define WS_EMBT 34816               // [34816..67584) embT[k][d]

// Prep (17 blocks x 512): b=0 exact norms; b=1..8 MFMA B-fragments with the
// -2 factor folded in (exact: *2 lossless in fp16); b=9..16 emb -> embT.
__global__ __launch_bounds__(512, 1) void prep_kernel(const float* __restrict__ emb,
                                                      float* __restrict__ ws) {
    const int tid = threadIdx.x;
    const int b   = blockIdx.x;
    if (b == 0) {
        float s = 0.f;
#pragma unroll
        for (int d = 0; d < DIM; ++d) { float v = emb[d * KCODES + tid]; s = fmaf(v, v, s); }
        ws[WS_EN + tid] = s;
    } else if (b <= 8) {
        const int fl = (b - 1) * 512 + tid;            // fragment-lane id, 0..4095
        const int ct = fl >> 7, s5 = (fl >> 6) & 1, l = fl & 63;
        const int k  = ct * 16 + (l & 15);             // B col
        const int d0 = s5 * 32 + (l >> 4) * 8;         // B k-rows (d)
        f16x8 eh, el;
#pragma unroll
        for (int e = 0; e < 8; ++e) {
            float v = emb[(d0 + e) * KCODES + k];
            _Float16 h = (_Float16)v;
            _Float16 l16 = (_Float16)((v - (float)h) * ELS);
            eh[e] = -(h + h);      // -2*h, exact
            el[e] = -(l16 + l16);  // -2*l, exact
        }
        ((f16x8*)(ws + WS_EH))[fl] = eh;
        ((f16x8*)(ws + WS_EL))[fl] = el;
    } else {
        __shared__ float tl[64][65];
        const int kt = b - 9;          // k-tile 0..7
        const int r  = tid >> 3;       // 0..63
        const int g  = tid & 7;
#pragma unroll
        for (int i = 0; i < 8; ++i)
            tl[r][g * 8 + i] = emb[r * KCODES + kt * 64 + g * 8 + i];
        __syncthreads();
#pragma unroll
        for (int i = 0; i < 8; ++i)
            ws[WS_EMBT + (kt * 64 + r) * 64 + g * 8 + i] = tl[g * 8 + i][r];
    }
}

// Main: 512 thr = 8 waves, VPB=128, grid 512 -> 4096 waves = 4 waves/SIMD.
// Slimmed scan loop: packed-u32 top-2 ((bits(sc+8) & ~31) | tile, k is
// lane-implicit -> 6 inst/score, no index registers), swap-free 2-deep
// register pipeline (loads land in the just-consumed set), accm split into
// two 2-deep MFMA chains. u64 lex merge; exact fp32 rescore when masked
// gap <= GAP_THR; embT epilogue; no atomics.
__global__ __launch_bounds__(512, 2) void vq_kernel(const float* __restrict__ x,
                                                    const float* __restrict__ ws_ro,
                                                    float* __restrict__ out,
                                                    float* __restrict__ part) {
    __shared__ f16x8 zhS[VPB][8];   // [v][u], u = (d>>3) ^ (v&7)  (bank swizzle)
    __shared__ f16x8 zlS[VPB][8];
    __shared__ float enS8[KCODES];  // en + BIAS (scan C-init)
    __shared__ int   cand[VPB][2];
    __shared__ float sdfm[VPB][2];  // biased masked scores (gap + fallback compare)
    __shared__ float exd[VPB][2];
    __shared__ int   bksel[VPB];
    __shared__ float swl[8];

    const int tid  = threadIdx.x;
    const int wid  = tid >> 6;            // 0..7
    const int lane = tid & 63;
    const size_t xbase = (size_t)blockIdx.x * VPB * DIM;

    enS8[tid] = ws_ro[WS_EN + tid] + BIAS;   // biased copy for the scan

    // x-block -> fp16 hi + scaled residual into swizzled LDS (4 thr/vector)
    {
        const int v  = tid >> 2;          // 0..127
        const int d0 = (tid & 3) * 16;
        const float* xp = x + xbase + v * DIM + d0;
        float4 a = *(const float4*)(xp);
        float4 b = *(const float4*)(xp + 4);
        float4 c = *(const float4*)(xp + 8);
        float4 e = *(const float4*)(xp + 12);
        float t0[8] = {a.x, a.y, a.z, a.w, b.x, b.y, b.z, b.w};
        float t1[8] = {c.x, c.y, c.z, c.w, e.x, e.y, e.z, e.w};
        f16x8 h0, l0, h1, l1;
#pragma unroll
        for (int i = 0; i < 8; ++i) {
            _Float16 h = (_Float16)t0[i]; h0[i] = h; l0[i] = (_Float16)((t0[i] - (float)h) * ELS);
            _Float16 g = (_Float16)t1[i]; h1[i] = g; l1[i] = (_Float16)((t1[i] - (float)g) * ELS);
        }
        const int u0 = ((d0 >> 3))     ^ (v & 7);
        const int u1 = ((d0 >> 3) + 1) ^ (v & 7);
        zhS[v][u0] = h0; zhS[v][u1] = h1;
        zlS[v][u0] = l0; zlS[v][u1] = l1;
    }
    __syncthreads();

    // A-fragments: row = lane&15 (vector), k = (lane>>4)*8 + e (+32 for 2nd)
    const int vb  = wid * 16;
    const int col = lane & 15;
    const int g4  = lane >> 4;
    const int vA  = vb + col;
    const int sw  = vA & 7;
    f16x8 ah0 = zhS[vA][(g4)     ^ sw];
    f16x8 ah1 = zhS[vA][(4 + g4) ^ sw];
    f16x8 al0 = zlS[vA][(g4)     ^ sw];
    f16x8 al1 = zlS[vA][(4 + g4) ^ sw];

    const f16x8* ehp = (const f16x8*)(ws_ro + WS_EH);
    const f16x8* elp = (const f16x8*)(ws_ro + WS_EL);

    unsigned b1[4] = {~0u, ~0u, ~0u, ~0u};
    unsigned b2[4] = {~0u, ~0u, ~0u, ~0u};

    // swap-free 2-deep pipeline: sets A (even tiles) and B (odd tiles)
    f16x8 Ah0 = ehp[lane],        Ah1 = ehp[64 + lane];
    f16x8 Al0 = elp[lane],        Al1 = elp[64 + lane];
    f16x8 Bh0 = ehp[128 + lane],  Bh1 = ehp[192 + lane];
    f16x8 Bl0 = elp[128 + lane],  Bl1 = elp[192 + lane];
    int onx = 256 + lane;                 // fragment index of tile ct+2

#define COMPUTE(T, H0, H1, L0, L1) { \
        const float enk8 = enS8[(T) * 16 + col]; \
        f32x4 acch  = {enk8, enk8, enk8, enk8}; \
        f32x4 accm1 = {0.f, 0.f, 0.f, 0.f}; \
        f32x4 accm2 = {0.f, 0.f, 0.f, 0.f}; \
        acch  = __builtin_amdgcn_mfma_f32_16x16x32_f16(ah0, H0, acch,  0, 0, 0); \
        acch  = __builtin_amdgcn_mfma_f32_16x16x32_f16(ah1, H1, acch,  0, 0, 0); \
        accm1 = __builtin_amdgcn_mfma_f32_16x16x32_f16(al0, H0, accm1, 0, 0, 0); \
        accm1 = __builtin_amdgcn_mfma_f32_16x16x32_f16(ah0, L0, accm1, 0, 0, 0); \
        accm2 = __builtin_amdgcn_mfma_f32_16x16x32_f16(al1, H1, accm2, 0, 0, 0); \
        accm2 = __builtin_amdgcn_mfma_f32_16x16x32_f16(ah1, L1, accm2, 0, 0, 0); \
        _Pragma("unroll") \
        for (int j = 0; j < 4; ++j) { \
            float scb = fmaf(accm1[j] + accm2[j], INV_ELS, acch[j]); \
            unsigned u = (__float_as_uint(scb) & 0xFFFFFFE0u) | (unsigned)(T); \
            b2[j] = min(b2[j], max(u, b1[j])); \
            b1[j] = min(b1[j], u); \
        } }

#pragma unroll 1
    for (int ct = 0; ct < 32; ct += 2) {
        COMPUTE(ct, Ah0, Ah1, Al0, Al1)
        // reload set A with tile ct+2 (tail iters read harmless ws garbage)
        Ah0 = ehp[onx]; Ah1 = ehp[onx + 64];
        Al0 = elp[onx]; Al1 = elp[onx + 64];
        COMPUTE(ct + 1, Bh0, Bh1, Bl0, Bl1)
        Bh0 = ehp[onx + 128]; Bh1 = ehp[onx + 192];
        Bl0 = elp[onx + 128]; Bl1 = elp[onx + 192];
        onx += 256;
    }
#undef COMPUTE

    // rebuild (masked-dist, k) as u64 and lex-merge top-2 across 16 lanes
    u64 q1[4], q2[4];
#pragma unroll
    for (int j = 0; j < 4; ++j) {
        q1[j] = ((u64)(b1[j] & 0xFFFFFFE0u) << 32) | (unsigned)((b1[j] & 31u) * 16 + col);
        q2[j] = ((u64)(b2[j] & 0xFFFFFFE0u) << 32) | (unsigned)((b2[j] & 31u) * 16 + col);
    }
#pragma unroll
    for (int m = 1; m <= 8; m <<= 1) {
#pragma unroll
        for (int j = 0; j < 4; ++j) {
            u64 qa = __shfl_xor(q1[j], m);
            u64 qb = __shfl_xor(q2[j], m);
            u64 lo = q1[j] < qa ? q1[j] : qa;
            u64 hi = q1[j] < qa ? qa : q1[j];
            u64 s2 = q2[j] < qb ? q2[j] : qb;
            q1[j] = lo;
            q2[j] = hi < s2 ? hi : s2;
        }
    }
    {
        const int j = lane & 15;
        if (j < 4) {                      // static-index extraction (rule #20)
            const int v = vb + g4 * 4 + j;
            u64 s1 = j == 0 ? q1[0] : j == 1 ? q1[1] : j == 2 ? q1[2] : q1[3];
            u64 s2 = j == 0 ? q2[0] : j == 1 ? q2[1] : j == 2 ? q2[2] : q2[3];
            sdfm[v][0] = __uint_as_float((unsigned)(s1 >> 32));  // biased, masked
            sdfm[v][1] = __uint_as_float((unsigned)(s2 >> 32));
            cand[v][0] = (int)(s1 & 0x1FFu);
            cand[v][1] = (int)(s2 & 0x1FFu);
        }
    }
    __syncthreads();

    // conditional exact rescore (reference-exact chain; exact en from ws)
    if (tid < 2 * VPB) {
        const int v = tid >> 1, cc = tid & 1;
        float res = sdfm[v][cc];          // biased fallback (consistent pair)
        if (sdfm[v][1] - sdfm[v][0] <= GAP_THR) {
            const int k = cand[v][cc];
            const float* xr = x + xbase + v * DIM;
            const float* er = ws_ro + WS_EMBT + k * 64;
            float zn = 0.f, dot = 0.f;
#pragma unroll
            for (int d = 0; d < DIM; ++d) {
                float xv = xr[d];
                zn  = fmaf(xv, xv, zn);
                dot = fmaf(xv, er[d], dot);
            }
            res = fmaf(-2.0f, dot, zn + ws_ro[WS_EN + k]);
        }
        exd[v][cc] = res;
    }
    __syncthreads();
    if (tid < VPB) {
        const int k0 = cand[tid][0], k1 = cand[tid][1];
        const float d0 = exd[tid][0], d1 = exd[tid][1];
        const bool take2 = (d1 < d0) || (d1 == d0 && k1 < k0);
        bksel[tid] = take2 ? k1 : k0;
    }
    __syncthreads();

    // epilogue: thread -> (vector v16, dim-block j16); q from embT rows
    const int v16 = tid >> 2;             // 0..127
    const int j16 = (tid & 3) * 16;
    const int bk  = bksel[v16];
    const int gvec = blockIdx.x * VPB + v16;
    const float*  xg  = x + (size_t)gvec * DIM + j16;
    float*        og  = out + (size_t)gvec * DIM + j16;
    const float4* et4 = (const float4*)(ws_ro + WS_EMBT + bk * 64);

    float lossLocal = 0.f;
#pragma unroll
    for (int c = 0; c < 4; ++c) {
        float4 q  = et4[(tid & 3) * 4 + c];
        *(float4*)(og + c * 4) = q;
        float4 xa = *(const float4*)(xg + c * 4);
        float a;
        a = q.x - xa.x; lossLocal = fmaf(a, a, lossLocal);
        a = q.y - xa.y; lossLocal = fmaf(a, a, lossLocal);
        a = q.z - xa.z; lossLocal = fmaf(a, a, lossLocal);
        a = q.w - xa.w; lossLocal = fmaf(a, a, lossLocal);
    }

    // block-reduce loss -> one partial store per block (no atomics)
#pragma unroll
    for (int off = 32; off; off >>= 1) lossLocal += __shfl_down(lossLocal, off, 64);
    if (lane == 0) swl[wid] = lossLocal;
    __syncthreads();
    if (tid == 0) {
        float s = 0.f;
#pragma unroll
        for (int i = 0; i < 8; ++i) s += swl[i];
        part[WS_PART + blockIdx.x] = s;
    }
}

// Finish: reduce 512 per-block partials, write the loss element.
__global__ __launch_bounds__(256, 1) void finish_kernel(const float* __restrict__ part,
                                                        float* __restrict__ out) {
    __shared__ float sw[4];
    const int tid = threadIdx.x, lane = tid & 63, wid = tid >> 6;
    float s = part[WS_PART + tid] + part[WS_PART + tid + 256];
#pragma unroll
    for (int off = 32; off; off >>= 1) s += __shfl_down(s, off, 64);
    if (lane == 0) sw[wid] = s;
    __syncthreads();
    if (tid == 0) {
        float total = sw[0] + sw[1] + sw[2] + sw[3];
        out[(size_t)NVEC * DIM] = 2.0f * total / (float)((size_t)NVEC * DIM);
    }
}

extern "C" void kernel_launch(void* const* d_in, const int* in_sizes, int n_in,
                              void* d_out, int out_size, void* d_ws, size_t ws_size,
                              hipStream_t stream) {
    const float* x   = (const float*)d_in[0];
    const float* emb = (const float*)d_in[1];
    float* out = (float*)d_out;
    float* ws  = (float*)d_ws;

    prep_kernel<<<dim3(17), dim3(512), 0, stream>>>(emb, ws);
    vq_kernel<<<dim3(NBLK), dim3(512), 0, stream>>>(x, ws, out, ws);
    finish_kernel<<<dim3(1), dim3(256), 0, stream>>>(ws, out);
}